// Round 8
// baseline (236.754 us; speedup 1.0000x reference)
//
#include <hip/hip_runtime.h>
#include <hip/hip_bf16.h>

#define LL 128
#define HH 768
#define OFF_REL  0
#define OFF_MASK 131072
#define OFF_HSRC 131840
#define OFF_HTGT 918272
#define SCALEC 2.8853900817779268f   // 2*log2(e):  e^{2x} = exp2(SCALEC*x)
#define NBLK 512

typedef __attribute__((ext_vector_type(8))) short short8;
typedef __attribute__((ext_vector_type(4))) float floatx4;

// Grid barrier: arrive with ONE device-scope RMW per block; spin with plain
// device-scope LOADS (no exclusive ownership -> no atomic-unit serialization).
__device__ __forceinline__ void gridbar(unsigned* c) {
  __syncthreads();
  if (threadIdx.x == 0) {
    __threadfence();   // release
    __hip_atomic_fetch_add(c, 1u, __ATOMIC_ACQ_REL, __HIP_MEMORY_SCOPE_AGENT);
    while (__hip_atomic_load(c, __ATOMIC_RELAXED, __HIP_MEMORY_SCOPE_AGENT) < NBLK)
      __builtin_amdgcn_s_sleep(16);
  }
  __syncthreads();
  __threadfence();     // acquire
}

__global__ __launch_bounds__(256, 2) void fused_kernel(
    const float4* __restrict__ hidden4,
    const float* __restrict__ Wsrc, const float* __restrict__ Wtgt,
    const float* __restrict__ Wd,
    const float* __restrict__ b_src, const float* __restrict__ b_tgt,
    const float* __restrict__ dense_b,
    const float* __restrict__ w_out, const float* __restrict__ clf_W,
    const float* __restrict__ clf_b,
    float* __restrict__ out,
    unsigned short* __restrict__ Ab, float* __restrict__ z,
    float* __restrict__ Es, float* __restrict__ Et,
    unsigned* __restrict__ cnt)
{
  __shared__ __align__(16) char smem[55296];
  int tid = threadIdx.x;
  int blk = blockIdx.x;
  int wave = tid >> 6, lane = tid & 63;

  // ---------- Phase 1: hidden fp32 -> bf16 ----------
  {
    int gid = blk * 256 + tid;
    if (gid < 49152) {
      float4 v = hidden4[gid];
      union { __hip_bfloat162 h2[2]; uint2 u2; } u;
      u.h2[0] = __float22bfloat162_rn(float2{v.x, v.y});
      u.h2[1] = __float22bfloat162_rn(float2{v.z, v.w});
      ((uint2*)Ab)[gid] = u.u2;
    }
  }
  gridbar(cnt + 0);

  // ---------- Phase 2: GEMM  A[256x768]bf16 x W[8448x768]^T ----------
  {
    typedef unsigned short (*sbw_t)[32][36];
    sbw_t sBw = (sbw_t)smem;      // [24][32][36] ushort = 54 KB
    int lr = lane & 15, lk8 = (lane >> 4) * 8;
    int sc = tid >> 3, t8 = tid & 7;

    #pragma unroll 1
    for (int t = blk; t < 528; t += NBLK) {
      int nb = t >> 1, by = t & 1;
      const float* W; int wrow0;
      if (nb < 96)       { W = Wsrc; wrow0 = nb * 32; }
      else if (nb < 192) { W = Wtgt; wrow0 = (nb - 96) * 32; }
      else               { W = Wd;   wrow0 = (nb - 192) * 32; }

      const float* wp = W + (long)(wrow0 + sc) * HH + t8 * 4;
      float4 wr[24];
      #pragma unroll
      for (int ch = 0; ch < 24; ++ch) wr[ch] = *(const float4*)(wp + ch * 32);
      #pragma unroll
      for (int ch = 0; ch < 24; ++ch) {
        union { __hip_bfloat162 h2[2]; uint2 u2; } u;
        u.h2[0] = __float22bfloat162_rn(float2{wr[ch].x, wr[ch].y});
        u.h2[1] = __float22bfloat162_rn(float2{wr[ch].z, wr[ch].w});
        *(uint2*)&sBw[ch][sc][t8 * 4] = u.u2;
      }

      const unsigned short* ap = Ab + (by * 128 + wave * 32 + lr) * HH + lk8;
      floatx4 acc[2][2];
      #pragma unroll
      for (int mi = 0; mi < 2; ++mi)
        #pragma unroll
        for (int ni = 0; ni < 2; ++ni)
          acc[mi][ni] = (floatx4){0.f, 0.f, 0.f, 0.f};

      __syncthreads();
      #pragma unroll 4
      for (int ks = 0; ks < 24; ++ks) {
        short8 a0 = *(const short8*)(ap + ks * 32);
        short8 a1 = *(const short8*)(ap + ks * 32 + 16 * HH);
        short8 b0 = *(const short8*)(&sBw[ks][lr][lk8]);
        short8 b1 = *(const short8*)(&sBw[ks][16 + lr][lk8]);
        acc[0][0] = __builtin_amdgcn_mfma_f32_16x16x32_bf16(a0, b0, acc[0][0], 0, 0, 0);
        acc[0][1] = __builtin_amdgcn_mfma_f32_16x16x32_bf16(a0, b1, acc[0][1], 0, 0, 0);
        acc[1][0] = __builtin_amdgcn_mfma_f32_16x16x32_bf16(a1, b0, acc[1][0], 0, 0, 0);
        acc[1][1] = __builtin_amdgcn_mfma_f32_16x16x32_bf16(a1, b1, acc[1][1], 0, 0, 0);
      }

      int lrow = (lane >> 4) * 4;
      #pragma unroll
      for (int mi = 0; mi < 2; ++mi)
      #pragma unroll
      for (int ni = 0; ni < 2; ++ni) {
        int col  = wrow0 + ni * 16 + lr;
        int row0 = by * 128 + wave * 32 + mi * 16 + lrow;
        if (nb < 96) {
          float bv = b_src[col];
          #pragma unroll
          for (int r2 = 0; r2 < 4; ++r2) {
            int row = row0 + r2;
            float v = acc[mi][ni][r2] + bv;
            out[OFF_HSRC + row * 3072 + col] = v;
            Es[row * 3072 + col] = __builtin_amdgcn_exp2f(SCALEC * v);
          }
        } else if (nb < 192) {
          float bv = b_tgt[col];
          #pragma unroll
          for (int r2 = 0; r2 < 4; ++r2) {
            int row = row0 + r2;
            float v = acc[mi][ni][r2] + bv;
            out[OFF_HTGT + row * 3072 + col] = v;
            Et[row * 3072 + col] = __builtin_amdgcn_exp2f(SCALEC * v);
          }
        } else {
          float bv = dense_b[col];
          #pragma unroll
          for (int r2 = 0; r2 < 4; ++r2)
            z[(row0 + r2) * 2304 + col] = acc[mi][ni][r2] + bv;
        }
      }
      __syncthreads();
    }
  }
  gridbar(cnt + 1);

  // ---------- Phase 3: token-mask head + pairwise relation ----------
  {
    float* sA  = (float*)smem;                 // [16][260]
    float* sB  = (float*)(smem + 16640);       // [16][260]
    float* sRd = (float*)(smem + 33280);       // [4 sl][4 g][64]
    float* sWs = (float*)(smem + 37376);
    float* sMr = (float*)(smem + 37392);       // [4]

    int u = blk;

    // mask head: rows u and u+512; 2 waves per row, 384-h halves
    {
      int ru = (wave < 2) ? u : u + NBLK;
      float accm = 0.f;
      if (ru < 768) {
        int gb = ru / 384, rm = ru % 384, tt = rm >> 7, lt = rm & 127;
        const float* zr = z + (size_t)(gb * 128 + lt) * 2304 + tt * 768 + (wave & 1) * 384;
        const float* cw = clf_W + (wave & 1) * 384;
        #pragma unroll
        for (int i = 0; i < 6; ++i) {
          int h = i * 64 + lane;
          float x = zr[h];
          float th = 1.f - 2.f * __builtin_amdgcn_rcpf(1.f + __builtin_amdgcn_exp2f(SCALEC * x));
          accm = fmaf(cw[h], th, accm);
        }
        #pragma unroll
        for (int d = 32; d; d >>= 1) accm += __shfl_down(accm, d);
      }
      if (lane == 0) sMr[wave] = accm;
    }
    // Wsum (wave 3, overlaps with mask finish)
    if (wave == 3) {
      float wsm = 0.f;
      for (int h = lane; h < HH; h += 64) wsm += w_out[h];
      #pragma unroll
      for (int d = 32; d; d >>= 1) wsm += __shfl_down(wsm, d);
      if (lane == 0) *sWs = wsm;
    }
    __syncthreads();
    if (tid == 0) out[OFF_MASK + u] = sMr[0] + sMr[1] + clf_b[0];
    if (tid == 64 && u + NBLK < 768) out[OFF_MASK + u + NBLK] = sMr[2] + sMr[3] + clf_b[0];

    // pair: rel[br, s0+s, t0+t] = Wsum - 2*sum_h w[h]/(1+Es*Et)
    int br = u >> 6, rem2 = u & 63;
    int s0 = (rem2 >> 3) * 16, t0 = (rem2 & 7) * 16;
    int bb = br >> 2, r = br & 3;
    int sq = lane >> 3, tq = lane & 7;
    int srow = tid >> 4, scbase = (tid & 15) * 16;
    int gof = wave * 64;
    const float* pes = Es + (size_t)(bb * LL + s0 + srow) * 3072 + r * HH;
    const float* pet = Et + (size_t)(bb * LL + t0 + srow) * 3072 + r * HH;

    float a00 = 0.f, a01 = 0.f, a10 = 0.f, a11 = 0.f;

    #pragma unroll 1
    for (int c = 0; c < HH; c += 256) {
      int offu = __builtin_amdgcn_readfirstlane(c + gof);
      float4 wv[16];
      #pragma unroll
      for (int q = 0; q < 16; ++q) wv[q] = *(const float4*)(w_out + offu + q * 4);

      __syncthreads();
      #pragma unroll
      for (int j = 0; j < 4; ++j) {
        int col4 = scbase + j * 4;
        *(float4*)(sA + srow * 260 + col4) = *(const float4*)(pes + c + col4);
        *(float4*)(sB + srow * 260 + col4) = *(const float4*)(pet + c + col4);
      }
      __syncthreads();

      const float* pA0 = sA + (2 * sq) * 260 + gof;
      const float* pA1 = sA + (2 * sq + 1) * 260 + gof;
      const float* pB0 = sB + (2 * tq) * 260 + gof;
      const float* pB1 = sB + (2 * tq + 1) * 260 + gof;
      #pragma unroll
      for (int hh = 0; hh < 64; hh += 4) {
        float4 e0 = *(const float4*)(pA0 + hh);
        float4 e1 = *(const float4*)(pA1 + hh);
        float4 f0 = *(const float4*)(pB0 + hh);
        float4 f1 = *(const float4*)(pB1 + hh);
        float4 vw = wv[hh >> 2];
        a00 = fmaf(vw.x, __builtin_amdgcn_rcpf(fmaf(e0.x, f0.x, 1.f)), a00);
        a01 = fmaf(vw.x, __builtin_amdgcn_rcpf(fmaf(e0.x, f1.x, 1.f)), a01);
        a10 = fmaf(vw.x, __builtin_amdgcn_rcpf(fmaf(e1.x, f0.x, 1.f)), a10);
        a11 = fmaf(vw.x, __builtin_amdgcn_rcpf(fmaf(e1.x, f1.x, 1.f)), a11);
        a00 = fmaf(vw.y, __builtin_amdgcn_rcpf(fmaf(e0.y, f0.y, 1.f)), a00);
        a01 = fmaf(vw.y, __builtin_amdgcn_rcpf(fmaf(e0.y, f1.y, 1.f)), a01);
        a10 = fmaf(vw.y, __builtin_amdgcn_rcpf(fmaf(e1.y, f0.y, 1.f)), a10);
        a11 = fmaf(vw.y, __builtin_amdgcn_rcpf(fmaf(e1.y, f1.y, 1.f)), a11);
        a00 = fmaf(vw.z, __builtin_amdgcn_rcpf(fmaf(e0.z, f0.z, 1.f)), a00);
        a01 = fmaf(vw.z, __builtin_amdgcn_rcpf(fmaf(e0.z, f1.z, 1.f)), a01);
        a10 = fmaf(vw.z, __builtin_amdgcn_rcpf(fmaf(e1.z, f0.z, 1.f)), a10);
        a11 = fmaf(vw.z, __builtin_amdgcn_rcpf(fmaf(e1.z, f1.z, 1.f)), a11);
        a00 = fmaf(vw.w, __builtin_amdgcn_rcpf(fmaf(e0.w, f0.w, 1.f)), a00);
        a01 = fmaf(vw.w, __builtin_amdgcn_rcpf(fmaf(e0.w, f1.w, 1.f)), a01);
        a10 = fmaf(vw.w, __builtin_amdgcn_rcpf(fmaf(e1.w, f0.w, 1.f)), a10);
        a11 = fmaf(vw.w, __builtin_amdgcn_rcpf(fmaf(e1.w, f1.w, 1.f)), a11);
      }
    }

    sRd[(0 * 4 + wave) * 64 + lane] = a00;
    sRd[(1 * 4 + wave) * 64 + lane] = a01;
    sRd[(2 * 4 + wave) * 64 + lane] = a10;
    sRd[(3 * 4 + wave) * 64 + lane] = a11;
    __syncthreads();
    {
      int s = tid >> 4, t2 = tid & 15;
      int pp = (s >> 1) * 8 + (t2 >> 1);
      int sl = (s & 1) * 2 + (t2 & 1);
      float sum = sRd[(sl * 4 + 0) * 64 + pp] + sRd[(sl * 4 + 1) * 64 + pp]
                + sRd[(sl * 4 + 2) * 64 + pp] + sRd[(sl * 4 + 3) * 64 + pp];
      out[((long)br * LL + (s0 + s)) * LL + (t0 + t2)] = *sWs - 2.f * sum;
    }
  }
}

extern "C" void kernel_launch(void* const* d_in, const int* in_sizes, int n_in,
                              void* d_out, int out_size, void* d_ws, size_t ws_size,
                              hipStream_t stream)
{
  const float* hidden  = (const float*)d_in[0];
  const float* W_src   = (const float*)d_in[1];
  const float* b_src   = (const float*)d_in[2];
  const float* W_tgt   = (const float*)d_in[3];
  const float* b_tgt   = (const float*)d_in[4];
  const float* w_out   = (const float*)d_in[5];
  const float* dense_W = (const float*)d_in[6];
  const float* dense_b = (const float*)d_in[7];
  const float* clf_W   = (const float*)d_in[8];
  const float* clf_b   = (const float*)d_in[9];
  float* out = (float*)d_out;
  char* ws = (char*)d_ws;

  unsigned short* Ab = (unsigned short*)ws;        // 256x768 bf16  [0, 384K)
  float* z  = (float*)(ws + 393216);               // 256x2304 f32
  float* Es = (float*)(ws + 2752512);              // 256x3072 f32
  float* Et = (float*)(ws + 5898240);              // 256x3072 f32
  unsigned* cnt = (unsigned*)(ws + 16777216);      // 2 barrier counters

  hipMemsetAsync(cnt, 0, 16, stream);
  hipLaunchKernelGGL(fused_kernel, dim3(NBLK), dim3(256), 0, stream,
      (const float4*)hidden, W_src, W_tgt, dense_W, b_src, b_tgt, dense_b,
      w_out, clf_W, clf_b, out, Ab, z, Es, Et, cnt);
}

// Round 9
// 65.205 us; speedup vs baseline: 3.6309x; 3.6309x over previous
//
#include <hip/hip_runtime.h>
#include <hip/hip_bf16.h>

#define LL 128
#define HH 768
#define OFF_REL  0
#define OFF_MASK 131072
#define OFF_HSRC 131840
#define OFF_HTGT 918272
#define SCALEC 2.8853900817779268f   // 2*log2(e):  e^{2x} = exp2(SCALEC*x)

typedef __attribute__((ext_vector_type(8))) short short8;
typedef __attribute__((ext_vector_type(4))) float floatx4;

__device__ __forceinline__ short8 pack8(float4 lo, float4 hi) {
  union { __hip_bfloat162 h2[4]; short8 s8; } u;
  u.h2[0] = __float22bfloat162_rn(float2{lo.x, lo.y});
  u.h2[1] = __float22bfloat162_rn(float2{lo.z, lo.w});
  u.h2[2] = __float22bfloat162_rn(float2{hi.x, hi.y});
  u.h2[3] = __float22bfloat162_rn(float2{hi.z, hi.w});
  return u.s8;
}

// ---------------- GEMM: A(hidden fp32, cvt in-reg) x W[8448x768]^T(fp32->LDS once) ----------------
// grid (264, 2) x 256 thr. Block = 32 cols x 128 rows (4 waves x 32 rows).
// W panel staged bf16 in LDS once; ONE barrier; A fragments loaded fp32 from L2.
__global__ __launch_bounds__(256, 2) void gemm_kernel(
    const float* __restrict__ hidden,
    const float* __restrict__ Wsrc, const float* __restrict__ Wtgt,
    const float* __restrict__ Wd,
    const float* __restrict__ b_src, const float* __restrict__ b_tgt,
    const float* __restrict__ dense_b,
    float* __restrict__ out, float* __restrict__ z,
    float* __restrict__ Es, float* __restrict__ Et)
{
  __shared__ unsigned short sB[24][32][36];   // [ks][col][k-in-chunk], 54 KB
  int nb = blockIdx.x;
  int by = blockIdx.y;
  int tid = threadIdx.x;
  int wave = tid >> 6, lane = tid & 63;

  const float* W; int wrow0;
  if (nb < 96)       { W = Wsrc; wrow0 = nb * 32; }
  else if (nb < 192) { W = Wtgt; wrow0 = (nb - 96) * 32; }
  else               { W = Wd;   wrow0 = (nb - 192) * 32; }

  // staging role: 8 threads cover one col's 768 k's
  int sc = tid >> 3, t8 = tid & 7;
  const float* wp = W + (long)(wrow0 + sc) * HH + t8 * 4;

  // prefetch whole W panel: 24 float4 per thread, all in flight
  float4 wr[24];
  #pragma unroll
  for (int ch = 0; ch < 24; ++ch) wr[ch] = *(const float4*)(wp + ch * 32);
  #pragma unroll
  for (int ch = 0; ch < 24; ++ch) {
    union { __hip_bfloat162 h2[2]; uint2 u2; } u;
    u.h2[0] = __float22bfloat162_rn(float2{wr[ch].x, wr[ch].y});
    u.h2[1] = __float22bfloat162_rn(float2{wr[ch].z, wr[ch].w});
    *(uint2*)&sB[ch][sc][t8 * 4] = u.u2;
  }

  // A fragment addressing (fp32, from hidden; L2-resident)
  int lr = lane & 15, lk8 = (lane >> 4) * 8;
  const float* hp0 = hidden + (long)(by * 128 + wave * 32 + lr) * HH + lk8;
  const float* hp1 = hp0 + 16 * HH;

  floatx4 acc[2][2];
  #pragma unroll
  for (int mi = 0; mi < 2; ++mi)
    #pragma unroll
    for (int ni = 0; ni < 2; ++ni)
      acc[mi][ni] = (floatx4){0.f, 0.f, 0.f, 0.f};

  __syncthreads();

  #pragma unroll 4
  for (int ks = 0; ks < 24; ++ks) {
    float4 af00 = *(const float4*)(hp0 + ks * 32);
    float4 af01 = *(const float4*)(hp0 + ks * 32 + 4);
    float4 af10 = *(const float4*)(hp1 + ks * 32);
    float4 af11 = *(const float4*)(hp1 + ks * 32 + 4);
    short8 a0 = pack8(af00, af01);
    short8 a1 = pack8(af10, af11);
    short8 b0 = *(const short8*)(&sB[ks][lr][lk8]);
    short8 b1 = *(const short8*)(&sB[ks][16 + lr][lk8]);
    acc[0][0] = __builtin_amdgcn_mfma_f32_16x16x32_bf16(a0, b0, acc[0][0], 0, 0, 0);
    acc[0][1] = __builtin_amdgcn_mfma_f32_16x16x32_bf16(a0, b1, acc[0][1], 0, 0, 0);
    acc[1][0] = __builtin_amdgcn_mfma_f32_16x16x32_bf16(a1, b0, acc[1][0], 0, 0, 0);
    acc[1][1] = __builtin_amdgcn_mfma_f32_16x16x32_bf16(a1, b1, acc[1][1], 0, 0, 0);
  }

  // epilogue
  int lrow = (lane >> 4) * 4;
  #pragma unroll
  for (int mi = 0; mi < 2; ++mi)
  #pragma unroll
  for (int ni = 0; ni < 2; ++ni) {
    int col  = wrow0 + ni * 16 + lr;
    int row0 = by * 128 + wave * 32 + mi * 16 + lrow;
    if (nb < 96) {
      float bv = b_src[col];
      #pragma unroll
      for (int r2 = 0; r2 < 4; ++r2) {
        int row = row0 + r2;
        float v = acc[mi][ni][r2] + bv;
        out[OFF_HSRC + row * 3072 + col] = v;
        Es[row * 3072 + col] = __builtin_amdgcn_exp2f(SCALEC * v);
      }
    } else if (nb < 192) {
      float bv = b_tgt[col];
      #pragma unroll
      for (int r2 = 0; r2 < 4; ++r2) {
        int row = row0 + r2;
        float v = acc[mi][ni][r2] + bv;
        out[OFF_HTGT + row * 3072 + col] = v;
        Et[row * 3072 + col] = __builtin_amdgcn_exp2f(SCALEC * v);
      }
    } else {
      float bv = dense_b[col];
      #pragma unroll
      for (int r2 = 0; r2 < 4; ++r2)
        z[(row0 + r2) * 2304 + col] = acc[mi][ni][r2] + bv;
    }
  }
}

// ---------------- pairwise relation + token-mask head ----------------
// rel[b,r,s,t] = Wsum - 2*sum_h w[h] / (1 + Es[s,h]*Et[t,h])
#define PHC 256
__global__ __launch_bounds__(512) void pair_kernel(
    const float* __restrict__ Es, const float* __restrict__ Et,
    const float* __restrict__ w_out,
    const float* __restrict__ z, const float* __restrict__ clf_W,
    const float* __restrict__ clf_b, float* __restrict__ out)
{
  int tid = threadIdx.x;

  if (blockIdx.z == 8) {
    // token mask head
    int blk = blockIdx.y * 8 + blockIdx.x;
    int wave = tid >> 6, lane = tid & 63;
    int slot = blk * 8 + wave;
    for (int o = slot; o < 768; o += 512) {
      int b = o / 384, rem = o - b * 384;
      int t = rem >> 7, lt = rem & 127;
      const float* zr = z + (long)(b * LL + lt) * 2304 + t * HH;
      float acc = 0.f;
      for (int h = lane; h < HH; h += 64) {
        float x = zr[h];
        float th = 1.f - 2.f * __builtin_amdgcn_rcpf(1.f + __builtin_amdgcn_exp2f(SCALEC * x));
        acc = fmaf(clf_W[h], th, acc);
      }
      #pragma unroll
      for (int d = 32; d; d >>= 1) acc += __shfl_down(acc, d);
      if (lane == 0) out[OFF_MASK + o] = acc + clf_b[0];
    }
    return;
  }

  __shared__ float sA[16][PHC + 4];
  __shared__ float sB[16][PHC + 4];
  __shared__ float sRed[2048];       // [k][g][p]
  __shared__ float sWsum;

  int g = tid >> 6, lane = tid & 63;
  int sq = lane >> 3, tq = lane & 7;
  int t0 = blockIdx.x * 16, s0 = blockIdx.y * 16;
  int br = blockIdx.z, bb = br >> 2, r = br & 3;

  if (tid < 64) {
    float wsm = 0.f;
    for (int h = tid; h < HH; h += 64) wsm += w_out[h];
    #pragma unroll
    for (int d = 32; d; d >>= 1) wsm += __shfl_down(wsm, d);
    if (tid == 0) sWsum = wsm;
  }

  float a00 = 0.f, a01 = 0.f, a10 = 0.f, a11 = 0.f;

  for (int c = 0; c < HH; c += PHC) {
    int offu = __builtin_amdgcn_readfirstlane(c + g * 32);
    float4 wv[8];
    #pragma unroll
    for (int q = 0; q < 8; ++q) wv[q] = *(const float4*)(w_out + offu + q * 4);

    __syncthreads();
    #pragma unroll
    for (int j = 0; j < 2; ++j) {
      int idx = tid * 2 + j;
      int row = idx >> 6, col4 = (idx & 63) * 4;
      *(float4*)&sA[row][col4] =
          *(const float4*)(Es + (long)(bb * LL + s0 + row) * 3072 + r * HH + c + col4);
      *(float4*)&sB[row][col4] =
          *(const float4*)(Et + (long)(bb * LL + t0 + row) * 3072 + r * HH + c + col4);
    }
    __syncthreads();

    const float* pA0 = &sA[2 * sq][g * 32];
    const float* pA1 = &sA[2 * sq + 1][g * 32];
    const float* pB0 = &sB[2 * tq][g * 32];
    const float* pB1 = &sB[2 * tq + 1][g * 32];
    #pragma unroll
    for (int hh = 0; hh < 32; hh += 4) {
      float4 e0 = *(const float4*)(pA0 + hh);
      float4 e1 = *(const float4*)(pA1 + hh);
      float4 f0 = *(const float4*)(pB0 + hh);
      float4 f1 = *(const float4*)(pB1 + hh);
      float4 vw = wv[hh >> 2];
      a00 = fmaf(vw.x, __builtin_amdgcn_rcpf(fmaf(e0.x, f0.x, 1.f)), a00);
      a01 = fmaf(vw.x, __builtin_amdgcn_rcpf(fmaf(e0.x, f1.x, 1.f)), a01);
      a10 = fmaf(vw.x, __builtin_amdgcn_rcpf(fmaf(e1.x, f0.x, 1.f)), a10);
      a11 = fmaf(vw.x, __builtin_amdgcn_rcpf(fmaf(e1.x, f1.x, 1.f)), a11);
      a00 = fmaf(vw.y, __builtin_amdgcn_rcpf(fmaf(e0.y, f0.y, 1.f)), a00);
      a01 = fmaf(vw.y, __builtin_amdgcn_rcpf(fmaf(e0.y, f1.y, 1.f)), a01);
      a10 = fmaf(vw.y, __builtin_amdgcn_rcpf(fmaf(e1.y, f0.y, 1.f)), a10);
      a11 = fmaf(vw.y, __builtin_amdgcn_rcpf(fmaf(e1.y, f1.y, 1.f)), a11);
      a00 = fmaf(vw.z, __builtin_amdgcn_rcpf(fmaf(e0.z, f0.z, 1.f)), a00);
      a01 = fmaf(vw.z, __builtin_amdgcn_rcpf(fmaf(e0.z, f1.z, 1.f)), a01);
      a10 = fmaf(vw.z, __builtin_amdgcn_rcpf(fmaf(e1.z, f0.z, 1.f)), a10);
      a11 = fmaf(vw.z, __builtin_amdgcn_rcpf(fmaf(e1.z, f1.z, 1.f)), a11);
      a00 = fmaf(vw.w, __builtin_amdgcn_rcpf(fmaf(e0.w, f0.w, 1.f)), a00);
      a01 = fmaf(vw.w, __builtin_amdgcn_rcpf(fmaf(e0.w, f1.w, 1.f)), a01);
      a10 = fmaf(vw.w, __builtin_amdgcn_rcpf(fmaf(e1.w, f0.w, 1.f)), a10);
      a11 = fmaf(vw.w, __builtin_amdgcn_rcpf(fmaf(e1.w, f1.w, 1.f)), a11);
    }
  }

  sRed[0 * 512 + g * 64 + lane] = a00;
  sRed[1 * 512 + g * 64 + lane] = a01;
  sRed[2 * 512 + g * 64 + lane] = a10;
  sRed[3 * 512 + g * 64 + lane] = a11;
  __syncthreads();
  if (tid < 256) {
    int s = tid >> 4, t = tid & 15;
    int pp = (s >> 1) * 8 + (t >> 1);
    int sl = (s & 1) * 2 + (t & 1);
    float sum = 0.f;
    #pragma unroll
    for (int gg = 0; gg < 8; ++gg) sum += sRed[sl * 512 + gg * 64 + pp];
    out[((long)br * LL + (s0 + s)) * LL + (t0 + t)] = sWsum - 2.f * sum;
  }
}

extern "C" void kernel_launch(void* const* d_in, const int* in_sizes, int n_in,
                              void* d_out, int out_size, void* d_ws, size_t ws_size,
                              hipStream_t stream)
{
  const float* hidden  = (const float*)d_in[0];
  const float* W_src   = (const float*)d_in[1];
  const float* b_src   = (const float*)d_in[2];
  const float* W_tgt   = (const float*)d_in[3];
  const float* b_tgt   = (const float*)d_in[4];
  const float* w_out   = (const float*)d_in[5];
  const float* dense_W = (const float*)d_in[6];
  const float* dense_b = (const float*)d_in[7];
  const float* clf_W   = (const float*)d_in[8];
  const float* clf_b   = (const float*)d_in[9];
  float* out = (float*)d_out;
  char* ws = (char*)d_ws;

  float* z  = (float*)(ws);                        // 256x2304 f32
  float* Es = (float*)(ws + 2359296);              // 256x3072 f32
  float* Et = (float*)(ws + 5505024);              // 256x3072 f32

  hipLaunchKernelGGL(gemm_kernel, dim3(264, 2), dim3(256), 0, stream,
      hidden, W_src, W_tgt, dense_W, b_src, b_tgt, dense_b, out, z, Es, Et);
  hipLaunchKernelGGL(pair_kernel, dim3(8, 8, 9), dim3(512), 0, stream,
      Es, Et, w_out, z, clf_W, clf_b, out + OFF_REL);
}